// Round 4
// baseline (195.473 us; speedup 1.0000x reference)
//
#include <hip/hip_runtime.h>

#define N_RAYS 65536
#define N_PTS 128
#define FEAT 3
#define FAR_DELTA 1e10f
#define ITERS 4
#define RAYS_PER_ITER 16                       // per block per iteration (4 waves x 4 rays)
#define RAYS_PER_BLOCK (RAYS_PER_ITER * ITERS) // 64

// Register-pipelined version of the verified R2 core: each wave processes 4
// rays per iteration (two 32-lane segments x two chains), ITERS iterations,
// with next-iteration global loads issued before current-iteration compute.
// No LDS / no barriers -> loads stay in flight during the shuffle chain.

struct Tile {
    float4 dA, rA, dB, rB;
    float4 fA0, fA1, fA2, fB0, fB1, fB2;
};

__device__ __forceinline__ Tile load_tile(const float* __restrict__ depth,
                                          const float* __restrict__ density,
                                          const float* __restrict__ feature,
                                          int rayA, int rayB, int s) {
    Tile t;
    t.dA = *(const float4*)(depth   + (size_t)rayA * N_PTS + 4 * s);
    t.rA = *(const float4*)(density + (size_t)rayA * N_PTS + 4 * s);
    t.dB = *(const float4*)(depth   + (size_t)rayB * N_PTS + 4 * s);
    t.rB = *(const float4*)(density + (size_t)rayB * N_PTS + 4 * s);
    const float4* fA = (const float4*)(feature + (size_t)rayA * (N_PTS * FEAT)) + 3 * s;
    const float4* fB = (const float4*)(feature + (size_t)rayB * (N_PTS * FEAT)) + 3 * s;
    t.fA0 = fA[0]; t.fA1 = fA[1]; t.fA2 = fA[2];
    t.fB0 = fB[0]; t.fB1 = fB[1]; t.fB2 = fB[2];
    return t;
}

__device__ __forceinline__ void compute_store(const Tile& t, int rayA, int rayB,
                                              int s, float* __restrict__ out) {
    float nxA = __shfl_down(t.dA.x, 1);
    float nxB = __shfl_down(t.dB.x, 1);
    const bool last = (s == 31);
    float tA0 = t.rA.x * (t.dA.y - t.dA.x);
    float tA1 = t.rA.y * (t.dA.z - t.dA.y);
    float tA2 = t.rA.z * (t.dA.w - t.dA.z);
    float tA3 = t.rA.w * (last ? FAR_DELTA : (nxA - t.dA.w));
    float tB0 = t.rB.x * (t.dB.y - t.dB.x);
    float tB1 = t.rB.y * (t.dB.z - t.dB.y);
    float tB2 = t.rB.z * (t.dB.w - t.dB.z);
    float tB3 = t.rB.w * (last ? FAR_DELTA : (nxB - t.dB.w));

    float pA = tA0 + tA1 + tA2 + tA3;
    float pB = tB0 + tB1 + tB2 + tB3;
    float eA = __shfl_up(pA, 1, 32);
    float eB = __shfl_up(pB, 1, 32);
    if (s == 0) { eA = 0.0f; eB = 0.0f; }
    #pragma unroll
    for (int off = 1; off < 32; off <<= 1) {
        float xA = __shfl_up(eA, off, 32);
        float xB = __shfl_up(eB, off, 32);
        if (s >= off) { eA += xA; eB += xB; }
    }

    float TA0 = __expf(-eA);
    float TA1 = __expf(-(eA + tA0));
    float TA2 = __expf(-(eA + tA0 + tA1));
    float TA3 = __expf(-(eA + tA0 + tA1 + tA2));
    float TA4 = __expf(-(eA + pA));
    float TB0 = __expf(-eB);
    float TB1 = __expf(-(eB + tB0));
    float TB2 = __expf(-(eB + tB0 + tB1));
    float TB3 = __expf(-(eB + tB0 + tB1 + tB2));
    float TB4 = __expf(-(eB + pB));
    float wA0 = TA0 - TA1, wA1 = TA1 - TA2, wA2 = TA2 - TA3, wA3 = TA3 - TA4;
    float wB0 = TB0 - TB1, wB1 = TB1 - TB2, wB2 = TB2 - TB3, wB3 = TB3 - TB4;

    float a0 = wA0 * t.fA0.x + wA1 * t.fA0.w + wA2 * t.fA1.z + wA3 * t.fA2.y;
    float a1 = wA0 * t.fA0.y + wA1 * t.fA1.x + wA2 * t.fA1.w + wA3 * t.fA2.z;
    float a2 = wA0 * t.fA0.z + wA1 * t.fA1.y + wA2 * t.fA2.x + wA3 * t.fA2.w;
    float a3 = wA0 * t.dA.x  + wA1 * t.dA.y  + wA2 * t.dA.z  + wA3 * t.dA.w;
    float b0 = wB0 * t.fB0.x + wB1 * t.fB0.w + wB2 * t.fB1.z + wB3 * t.fB2.y;
    float b1 = wB0 * t.fB0.y + wB1 * t.fB1.x + wB2 * t.fB1.w + wB3 * t.fB2.z;
    float b2 = wB0 * t.fB0.z + wB1 * t.fB1.y + wB2 * t.fB2.x + wB3 * t.fB2.w;
    float b3 = wB0 * t.dB.x  + wB1 * t.dB.y  + wB2 * t.dB.z  + wB3 * t.dB.w;

    #pragma unroll
    for (int off = 16; off > 0; off >>= 1) {
        a0 += __shfl_down(a0, off, 32);
        a1 += __shfl_down(a1, off, 32);
        a2 += __shfl_down(a2, off, 32);
        a3 += __shfl_down(a3, off, 32);
        b0 += __shfl_down(b0, off, 32);
        b1 += __shfl_down(b1, off, 32);
        b2 += __shfl_down(b2, off, 32);
        b3 += __shfl_down(b3, off, 32);
    }

    if (s == 0) {
        *(float4*)(out + (size_t)rayA * 4) = make_float4(a0, a1, a2, a3);
        *(float4*)(out + (size_t)rayB * 4) = make_float4(b0, b1, b2, b3);
    }
}

__global__ __launch_bounds__(256) void volrend_kernel(
    const float* __restrict__ depth,
    const float* __restrict__ density,
    const float* __restrict__ feature,
    float* __restrict__ out)
{
    const int wv  = threadIdx.x >> 6;
    const int ln  = threadIdx.x & 63;
    const int seg = ln >> 5;
    const int s   = ln & 31;

    const int base  = blockIdx.x * RAYS_PER_BLOCK + wv * 4 + seg;
    const int rayA0 = base;         // + i*RAYS_PER_ITER per iteration
    const int rayB0 = base + 2;

    Tile t = load_tile(depth, density, feature, rayA0, rayB0, s);
    #pragma unroll
    for (int i = 0; i < ITERS; ++i) {
        Tile n;
        if (i + 1 < ITERS) {
            n = load_tile(depth, density, feature,
                          rayA0 + (i + 1) * RAYS_PER_ITER,
                          rayB0 + (i + 1) * RAYS_PER_ITER, s);
        }
        compute_store(t, rayA0 + i * RAYS_PER_ITER, rayB0 + i * RAYS_PER_ITER,
                      s, out);
        if (i + 1 < ITERS) t = n;
    }
}

extern "C" void kernel_launch(void* const* d_in, const int* in_sizes, int n_in,
                              void* d_out, int out_size, void* d_ws, size_t ws_size,
                              hipStream_t stream) {
    const float* depth   = (const float*)d_in[0];
    const float* density = (const float*)d_in[1];
    const float* feature = (const float*)d_in[2];
    float* out = (float*)d_out;

    dim3 grid(N_RAYS / RAYS_PER_BLOCK);   // 1024 blocks x 64 rays
    dim3 block(256);
    volrend_kernel<<<grid, block, 0, stream>>>(depth, density, feature, out);
}

// Round 5
// 189.818 us; speedup vs baseline: 1.0298x; 1.0298x over previous
//
#include <hip/hip_runtime.h>

#define N_RAYS 65536
#define N_PTS 128
#define FEAT 3
#define FAR_DELTA 1e10f

// R1 structure — empirically the fastest (60.4-60.8 us kernel dispatch), which
// sits exactly on the measured per-CU outstanding-read ceiling:
//   ~4 KB in-flight reads/CU / ~900 cyc HBM-class latency = 4.5 B/cyc/CU
//   => 169 MB / 2.80 TB/s = 60.4 us floor.
// R2 (4-ray ILP), R3 (global_load_lds L1 bypass), R4 (register pipeline) all
// landed 61-67 us; L3-warm replays identical => latency-capped, not BW/VALU.
//
// One 64-lane wave per ray; lane L owns samples 2L and 2L+1. Exclusive prefix
// sum of per-pair tau via shift-then-inclusive wave scan (keeps the 1e10
// sentinel tau out of every exclusive sum -> no cancellation).
__global__ __launch_bounds__(256) void volrend_kernel(
    const float* __restrict__ depth,
    const float* __restrict__ density,
    const float* __restrict__ feature,
    float* __restrict__ out)
{
    const int wave = threadIdx.x >> 6;
    const int lane = threadIdx.x & 63;
    const int ray  = (blockIdx.x << 2) + wave;

    const int base = ray * N_PTS;          // ray-contiguous layout
    const float2 d   = *(const float2*)(depth   + base + 2 * lane);
    const float2 rho = *(const float2*)(density + base + 2 * lane);

    // delta for sample 2L is d.y - d.x; delta for 2L+1 needs next lane's d.x.
    float next_dx = __shfl_down(d.x, 1);
    float delta_a = d.y - d.x;
    float delta_b = (lane == 63) ? FAR_DELTA : (next_dx - d.y);

    float tau_a = rho.x * delta_a;
    float tau_b = rho.y * delta_b;     // lane 63: ~1e10 * density (sentinel)
    float pair  = tau_a + tau_b;

    // Exclusive wave scan: shift by 1 (lane0 -> 0), then inclusive scan.
    float e = __shfl_up(pair, 1);
    if (lane == 0) e = 0.0f;
    #pragma unroll
    for (int off = 1; off < 64; off <<= 1) {
        float t = __shfl_up(e, off);
        if (lane >= off) e += t;
    }
    // e = sum of pair-taus of lanes < L = cum tau before sample 2L

    float Ta   = __expf(-e);                          // T at sample 2L
    float Tmid = __expf(-(e + tau_a));                // T at sample 2L+1
    float Tend = __expf(-(e + tau_a + tau_b));        // T after pair (0 @63)
    float w_a = Ta - Tmid;       // = T * (1 - exp(-tau))
    float w_b = Tmid - Tend;

    const float2* f2 = (const float2*)(feature + (size_t)ray * (N_PTS * FEAT)
                                       + 6 * lane);
    float2 fa = f2[0];   // feat[2L].rgb = fa.x fa.y fb.x
    float2 fb = f2[1];   // feat[2L+1].rgb = fb.y fc.x fc.y
    float2 fc = f2[2];

    float acc0 = w_a * fa.x + w_b * fb.y;
    float acc1 = w_a * fa.y + w_b * fc.x;
    float acc2 = w_a * fb.x + w_b * fc.y;
    float acc3 = w_a * d.x  + w_b * d.y;   // depth_out

    #pragma unroll
    for (int off = 32; off > 0; off >>= 1) {
        acc0 += __shfl_down(acc0, off);
        acc1 += __shfl_down(acc1, off);
        acc2 += __shfl_down(acc2, off);
        acc3 += __shfl_down(acc3, off);
    }

    if (lane == 0) {
        *(float4*)(out + ray * 4) = make_float4(acc0, acc1, acc2, acc3);
    }
}

extern "C" void kernel_launch(void* const* d_in, const int* in_sizes, int n_in,
                              void* d_out, int out_size, void* d_ws, size_t ws_size,
                              hipStream_t stream) {
    const float* depth   = (const float*)d_in[0];
    const float* density = (const float*)d_in[1];
    const float* feature = (const float*)d_in[2];
    float* out = (float*)d_out;

    // 4 rays per 256-thread block (one wave per ray)
    dim3 grid(N_RAYS / 4);
    dim3 block(256);
    volrend_kernel<<<grid, block, 0, stream>>>(depth, density, feature, out);
}